// Round 6
// baseline (276.261 us; speedup 1.0000x reference)
//
#include <hip/hip_runtime.h>
#include <hip/hip_bf16.h>

#define N 8192
#define D 1024
#define MARGIN 1.0f
#define EPS 1e-6f

typedef __attribute__((ext_vector_type(8))) short bf16x8;
typedef __attribute__((ext_vector_type(4))) float f32x4;
typedef __attribute__((ext_vector_type(8))) _Float16 f16x8;
typedef __attribute__((ext_vector_type(4))) _Float16 f16x4;

__device__ inline unsigned short f2bf(float x) {
    unsigned u = __float_as_uint(x);
    unsigned r = (u + 0x7FFFu + ((u >> 16) & 1u)) >> 16;  // RNE
    return (unsigned short)r;
}

// Kernel 0: fp32 -> bf16 copy + per-row sum of squares.
__global__ __launch_bounds__(256) void prep_kernel(const float* __restrict__ E,
                                                   unsigned short* __restrict__ Ebf,
                                                   float* __restrict__ sq) {
    const int r = blockIdx.x;
    const int tid = threadIdx.x;
    const float4 v = ((const float4*)(E + (size_t)r * D))[tid];
    ushort4 o;
    o.x = f2bf(v.x); o.y = f2bf(v.y); o.z = f2bf(v.z); o.w = f2bf(v.w);
    ((ushort4*)(Ebf + (size_t)r * D))[tid] = o;
    float s = v.x * v.x + v.y * v.y + v.z * v.z + v.w * v.w;
    for (int off = 32; off > 0; off >>= 1) s += __shfl_down(s, off);
    __shared__ float red[4];
    const int lane = tid & 63, wave = tid >> 6;
    if (lane == 0) red[wave] = s;
    __syncthreads();
    if (tid == 0) sq[r] = red[0] + red[1] + red[2] + red[3];
}

// Kernel 0b: target int32 -> uchar class ids (N_CLASSES=128 fits).
__global__ __launch_bounds__(256) void cls_kernel(const int* __restrict__ target,
                                                  unsigned char* __restrict__ cls) {
    const int t = blockIdx.x * 256 + threadIdx.x;
    cls[t] = (unsigned char)target[t];
}

// Kernel 1: symmetric D2 + fused pass-1 mining partials.
// Lower-triangular 128x128 blocks (by >= bx). Each block writes:
//   - direct tile + mirror tile of fp16 d2
//   - per-row partial hardest-pos (u32 max) / hardest-neg (u32 min) for its
//     128 direct rows (slot bx) and 128 mirror rows (slot by, skip if diag).
// u32 pack: (fp16 bits << 13) | col_idx  -- same ordering/tie-breaks as fp32 pack.
__global__ __launch_bounds__(256) void gemm_kernel(const unsigned short* __restrict__ E,
                                                   const float* __restrict__ sq,
                                                   const unsigned char* __restrict__ cls,
                                                   _Float16* __restrict__ D2h,
                                                   unsigned* __restrict__ Ppart,
                                                   unsigned* __restrict__ Npart) {
    __shared__ char smem[128 * 136 * 2];                  // 34816 B
    unsigned short* As = (unsigned short*)smem;           // 8 KB (K-loop)
    unsigned short* Bs = (unsigned short*)(smem + 8192);  // 8 KB (K-loop)
    _Float16* Ts = (_Float16*)smem;                       // epilogue transpose stage
    // mining scratch (aliases As/Bs after K-loop):
    unsigned* rpmax_l = (unsigned*)smem;                  // [128][2] 1 KB
    unsigned* rpmin_l = (unsigned*)(smem + 1024);
    unsigned* cpmax_l = (unsigned*)(smem + 2048);
    unsigned* cpmin_l = (unsigned*)(smem + 3072);
    float* sqr_l = (float*)(smem + 4096);                 // 512 B
    float* sqc_l = (float*)(smem + 4608);
    unsigned char* clr_l = (unsigned char*)(smem + 5120); // 128 B
    unsigned char* clc_l = (unsigned char*)(smem + 5248);

    const int tid = threadIdx.x;
    const int lane = tid & 63;
    const int wave = tid >> 6;
    const int wm = wave & 1, wn = wave >> 1;

    // decode linear block id -> (bx, by) with by >= bx
    const int l = blockIdx.x;
    int by = (int)((sqrtf(8.0f * (float)l + 1.0f) - 1.0f) * 0.5f);
    while ((by + 1) * (by + 2) / 2 <= l) ++by;
    while (by * (by + 1) / 2 > l) --by;
    const int bx = l - by * (by + 1) / 2;
    const int rm = by * 128;
    const int cn = bx * 128;

    const int srow = tid >> 2;
    const int scol = (tid & 3) * 8;

    const unsigned short* gA = E + (size_t)(rm + srow) * D + scol;
    const unsigned short* gB = E + (size_t)(cn + srow) * D + scol;

    f32x4 acc[4][4] = {};

    const int kq = (lane >> 4) * 8;
    const int mr = lane & 15;

    for (int k0 = 0; k0 < D; k0 += 32) {
        __builtin_amdgcn_global_load_lds(
            (const __attribute__((address_space(1))) unsigned int*)(gA + k0),
            (__attribute__((address_space(3))) unsigned int*)((char*)As + wave * 1024), 16, 0, 0);
        __builtin_amdgcn_global_load_lds(
            (const __attribute__((address_space(1))) unsigned int*)(gA + (size_t)64 * D + k0),
            (__attribute__((address_space(3))) unsigned int*)((char*)As + 4096 + wave * 1024), 16, 0, 0);
        __builtin_amdgcn_global_load_lds(
            (const __attribute__((address_space(1))) unsigned int*)(gB + k0),
            (__attribute__((address_space(3))) unsigned int*)((char*)Bs + wave * 1024), 16, 0, 0);
        __builtin_amdgcn_global_load_lds(
            (const __attribute__((address_space(1))) unsigned int*)(gB + (size_t)64 * D + k0),
            (__attribute__((address_space(3))) unsigned int*)((char*)Bs + 4096 + wave * 1024), 16, 0, 0);
        __syncthreads();

        bf16x8 af[4], bfr[4];
#pragma unroll
        for (int mi = 0; mi < 4; ++mi)
            af[mi] = *(const bf16x8*)(As + (wm * 64 + mi * 16 + mr) * 32 + kq);
#pragma unroll
        for (int ni = 0; ni < 4; ++ni)
            bfr[ni] = *(const bf16x8*)(Bs + (wn * 64 + ni * 16 + mr) * 32 + kq);
#pragma unroll
        for (int mi = 0; mi < 4; ++mi)
#pragma unroll
            for (int ni = 0; ni < 4; ++ni)
                acc[mi][ni] = __builtin_amdgcn_mfma_f32_16x16x32_bf16(af[mi], bfr[ni], acc[mi][ni], 0, 0, 0);
        __syncthreads();
    }

    const int crow = (lane >> 4) * 4;
    const int ccol = lane & 15;
    const int rg = lane >> 4;
    const bool offdiag = (bx != by);

    // ---- Phase M0: stage sq + cls tiles ----
    if (tid < 128) { sqr_l[tid] = sq[rm + tid]; clr_l[tid] = cls[rm + tid]; }
    else           { sqc_l[tid - 128] = sq[cn + tid - 128]; clc_l[tid - 128] = cls[cn + tid - 128]; }
    __syncthreads();

    unsigned char ccl[4]; float scl[4];
#pragma unroll
    for (int ni = 0; ni < 4; ++ni) {
        const int lc = wn * 64 + ni * 16 + ccol;
        ccl[ni] = clc_l[lc]; scl[ni] = sqc_l[lc];
    }

    // ---- Phase M1a: row partials (direct rows, this wave's 64-col half) ----
#pragma unroll
    for (int mi = 0; mi < 4; ++mi) {
#pragma unroll
        for (int r = 0; r < 4; ++r) {
            const int lrow = wm * 64 + mi * 16 + rg * 4 + r;
            const int gi = rm + lrow;
            const unsigned char rc = clr_l[lrow];
            const float sr = sqr_l[lrow];
            unsigned pm = 0u, nm = 0xFFFFFFFFu;
#pragma unroll
            for (int ni = 0; ni < 4; ++ni) {
                const int gj = cn + wn * 64 + ni * 16 + ccol;
                float d2 = fmaxf(fmaf(-2.0f, acc[mi][ni][r], sr + scl[ni]), 0.0f);
                _Float16 h = (_Float16)d2;
                unsigned hb = (unsigned)__builtin_bit_cast(unsigned short, h);
                unsigned pk = (hb << 13) | (unsigned)gj;
                if (ccl[ni] == rc) { if (gj != gi && pk > pm) pm = pk; }
                else if (pk < nm) nm = pk;
            }
#pragma unroll
            for (int m = 1; m < 16; m <<= 1) {
                unsigned a = __shfl_xor(pm, m); if (a > pm) pm = a;
                unsigned b = __shfl_xor(nm, m); if (b < nm) nm = b;
            }
            if (ccol == 0) { rpmax_l[lrow * 2 + wn] = pm; rpmin_l[lrow * 2 + wn] = nm; }
        }
    }

    // ---- Phase M1b: col partials (mirror rows), skip for diagonal ----
    if (offdiag) {
#pragma unroll
        for (int ni = 0; ni < 4; ++ni) {
            const int lcol = wn * 64 + ni * 16 + ccol;
            const int gj = cn + lcol;
            const unsigned char cc = ccl[ni];
            const float sc = scl[ni];
            unsigned pm = 0u, nm = 0xFFFFFFFFu;
#pragma unroll
            for (int mi = 0; mi < 4; ++mi) {
#pragma unroll
                for (int r = 0; r < 4; ++r) {
                    const int lrow = wm * 64 + mi * 16 + rg * 4 + r;
                    const int gi = rm + lrow;
                    float d2 = fmaxf(fmaf(-2.0f, acc[mi][ni][r], sqr_l[lrow] + sc), 0.0f);
                    _Float16 h = (_Float16)d2;
                    unsigned hb = (unsigned)__builtin_bit_cast(unsigned short, h);
                    unsigned pk = (hb << 13) | (unsigned)gi;
                    if (clr_l[lrow] == cc) { if (gi != gj && pk > pm) pm = pk; }
                    else if (pk < nm) nm = pk;
                }
            }
#pragma unroll
            for (int m = 16; m < 64; m <<= 1) {
                unsigned a = __shfl_xor(pm, m); if (a > pm) pm = a;
                unsigned b = __shfl_xor(nm, m); if (b < nm) nm = b;
            }
            if (rg == 0) { cpmax_l[lcol * 2 + wm] = pm; cpmin_l[lcol * 2 + wm] = nm; }
        }
    }
    __syncthreads();

    // ---- Phase M2: combine halves, write partials (each (slot,row) once) ----
    if (tid < 128) {
        unsigned pm = max(rpmax_l[tid * 2], rpmax_l[tid * 2 + 1]);
        unsigned nm = min(rpmin_l[tid * 2], rpmin_l[tid * 2 + 1]);
        Ppart[(size_t)bx * N + rm + tid] = pm;
        Npart[(size_t)bx * N + rm + tid] = nm;
    } else if (offdiag) {
        const int t = tid - 128;
        unsigned pm = max(cpmax_l[t * 2], cpmax_l[t * 2 + 1]);
        unsigned nm = min(cpmin_l[t * 2], cpmin_l[t * 2 + 1]);
        Ppart[(size_t)by * N + cn + t] = pm;
        Npart[(size_t)by * N + cn + t] = nm;
    }
    __syncthreads();   // LDS about to be reused as Ts

    // ---- Store phase: direct tile (+ Ts transposed stage for mirror) ----
    float sqj[4];
#pragma unroll
    for (int ni = 0; ni < 4; ++ni)
        sqj[ni] = sq[cn + wn * 64 + ni * 16 + ccol];
#pragma unroll
    for (int mi = 0; mi < 4; ++mi) {
        const int lrow = wm * 64 + mi * 16 + crow;
        const int i0 = rm + lrow;
        float sqi[4];
#pragma unroll
        for (int r = 0; r < 4; ++r) sqi[r] = sq[i0 + r];
#pragma unroll
        for (int ni = 0; ni < 4; ++ni) {
            const int lcol = wn * 64 + ni * 16 + ccol;
            const int j = cn + lcol;
            f16x4 tv;
#pragma unroll
            for (int r = 0; r < 4; ++r) {
                float d2 = fmaxf(fmaf(-2.0f, acc[mi][ni][r], sqi[r] + sqj[ni]), 0.0f);
                _Float16 h = (_Float16)d2;
                D2h[(size_t)(i0 + r) * N + j] = h;
                tv[r] = h;
            }
            if (offdiag)
                *(f16x4*)(Ts + (size_t)lcol * 136 + lrow) = tv;
        }
    }
    if (offdiag) {
        __syncthreads();
#pragma unroll
        for (int it = 0; it < 8; ++it) {
            const int rt = it * 16 + (tid >> 4);
            const int seg = tid & 15;
            f16x8 v = *(const f16x8*)(Ts + (size_t)rt * 136 + seg * 8);
            *(f16x8*)(D2h + (size_t)(cn + rt) * N + rm + seg * 8) = v;
        }
    }
}

// Kernel 2: fold 64 slots/row -> lo/hi window + pos idx + fallback-neg idx.
__global__ __launch_bounds__(256) void reduce2_kernel(const unsigned* __restrict__ Ppart,
                                                      const unsigned* __restrict__ Npart,
                                                      float2* __restrict__ lohi,
                                                      int2* __restrict__ pn) {
    const int row = blockIdx.x * 256 + threadIdx.x;
    unsigned pm = 0u, nm = 0xFFFFFFFFu;
    for (int s = 0; s < 64; ++s) {
        pm = max(pm, Ppart[(size_t)s * N + row]);
        nm = min(nm, Npart[(size_t)s * N + row]);
    }
    const float lo = (float)__builtin_bit_cast(_Float16, (unsigned short)((pm >> 13) & 0xFFFFu));
    const float hh = sqrtf(lo) + MARGIN;
    lohi[row] = make_float2(lo, hh * hh);
    pn[row] = make_int2((int)(pm & 8191u), (int)(nm & 8191u));
}

// Kernel 3: one wave per row, SINGLE streaming pass. No class data needed:
// d2 > lo (strict) excludes all positives (lo = max positive d2) and self.
// m2 = min{(d2,idx) : d2 > lo}; semi-hard iff m2.d2 < hi, else fallback.
__global__ __launch_bounds__(256) void mine2_kernel(const _Float16* __restrict__ D2h,
                                                    const float2* __restrict__ lohi,
                                                    const int2* __restrict__ pn,
                                                    const float* __restrict__ E,
                                                    float* __restrict__ loss_arr) {
    const int tid = threadIdx.x;
    const int lane = tid & 63, wave = tid >> 6;
    const int i = blockIdx.x * 4 + wave;
    const float2 lh = lohi[i];
    const float lo = lh.x, hi = lh.y;
    const _Float16* row = D2h + (size_t)i * N;

    unsigned long long m2 = ~0ull;
#pragma unroll
    for (int it = 0; it < 16; ++it) {
        const int jb = it * 512 + lane * 8;
        const f16x8 v = *(const f16x8*)(row + jb);
#pragma unroll
        for (int e = 0; e < 8; ++e) {
            const float d2 = (float)v[e];
            if (d2 > lo) {
                const unsigned long long pk =
                    ((unsigned long long)__float_as_uint(d2) << 32) | (unsigned)(jb + e);
                if (pk < m2) m2 = pk;
            }
        }
    }
    for (int off = 1; off < 64; off <<= 1) {
        unsigned long long t = __shfl_xor(m2, off); if (t < m2) m2 = t;
    }
    const int2 pnn = pn[i];
    const int pi = pnn.x;
    const float m2v = __uint_as_float((unsigned)(m2 >> 32));  // NaN if none found
    const int ni = (m2v < hi) ? (int)(unsigned)(m2 & 0xFFFFFFFFu) : pnn.y;

    // Fused loss: exact fp32 dp/dn (reference +EPS semantics), wave-parallel over D.
    const float4* Ea = (const float4*)(E + (size_t)i * D);
    const float4* Ep = (const float4*)(E + (size_t)pi * D);
    const float4* En = (const float4*)(E + (size_t)ni * D);
    float s1 = 0.0f, s2 = 0.0f;
#pragma unroll
    for (int c = 0; c < 4; ++c) {
        const int idx = c * 64 + lane;
        const float4 a = Ea[idx];
        const float4 p = Ep[idx];
        const float4 n = En[idx];
        float t;
        t = a.x - p.x + EPS; s1 += t * t;
        t = a.y - p.y + EPS; s1 += t * t;
        t = a.z - p.z + EPS; s1 += t * t;
        t = a.w - p.w + EPS; s1 += t * t;
        t = a.x - n.x + EPS; s2 += t * t;
        t = a.y - n.y + EPS; s2 += t * t;
        t = a.z - n.z + EPS; s2 += t * t;
        t = a.w - n.w + EPS; s2 += t * t;
    }
    for (int off = 1; off < 64; off <<= 1) {
        s1 += __shfl_xor(s1, off);
        s2 += __shfl_xor(s2, off);
    }
    if (lane == 0)
        loss_arr[i] = fmaxf(sqrtf(s1) - sqrtf(s2) + MARGIN, 0.0f);
}

// Kernel 4: mean over 8192 per-anchor losses.
__global__ __launch_bounds__(256) void reduce_kernel(const float* __restrict__ loss_arr,
                                                     float* __restrict__ out) {
    const int tid = threadIdx.x;
    float s = 0.0f;
    for (int k = tid; k < N; k += 256) s += loss_arr[k];
    for (int off = 32; off > 0; off >>= 1) s += __shfl_down(s, off);
    __shared__ float red[4];
    const int lane = tid & 63, wave = tid >> 6;
    if (lane == 0) red[wave] = s;
    __syncthreads();
    if (tid == 0) out[0] = (red[0] + red[1] + red[2] + red[3]) * (1.0f / N);
}

extern "C" void kernel_launch(void* const* d_in, const int* in_sizes, int n_in,
                              void* d_out, int out_size, void* d_ws, size_t ws_size,
                              hipStream_t stream) {
    const float* E = (const float*)d_in[0];
    const int* target = (const int*)d_in[1];
    float* out = (float*)d_out;
    char* ws = (char*)d_ws;

    // Workspace layout (~148.2 MB total):
    unsigned short* Ebf = (unsigned short*)ws;                            // 16 MB
    float* sq        = (float*)(ws + (size_t)16777216);                   // 32 KB
    float* loss_arr  = (float*)(ws + (size_t)16809984);                   // 32 KB
    unsigned char* cls = (unsigned char*)(ws + (size_t)16842752);         // 8 KB (padded 32 KB)
    float2* lohi     = (float2*)(ws + (size_t)16875520);                  // 64 KB
    int2* pn         = (int2*)(ws + (size_t)16941056);                    // 64 KB
    unsigned* Ppart  = (unsigned*)(ws + (size_t)17006592);                // 2 MB
    unsigned* Npart  = (unsigned*)(ws + (size_t)19103744);                // 2 MB
    _Float16* D2h    = (_Float16*)(ws + (size_t)21200896);                // 128 MB

    prep_kernel<<<N, 256, 0, stream>>>(E, Ebf, sq);
    cls_kernel<<<N / 256, 256, 0, stream>>>(target, cls);
    gemm_kernel<<<2080, 256, 0, stream>>>(Ebf, sq, cls, D2h, Ppart, Npart);
    reduce2_kernel<<<N / 256, 256, 0, stream>>>(Ppart, Npart, lohi, pn);
    mine2_kernel<<<N / 4, 256, 0, stream>>>(D2h, lohi, pn, E, loss_arr);
    reduce_kernel<<<1, 256, 0, stream>>>(loss_arr, out);
}

// Round 7
// 207.570 us; speedup vs baseline: 1.3309x; 1.3309x over previous
//
#include <hip/hip_runtime.h>
#include <hip/hip_bf16.h>

#define N 8192
#define D 1024
#define MARGIN 1.0f
#define EPS 1e-6f

typedef __attribute__((ext_vector_type(8))) short bf16x8;
typedef __attribute__((ext_vector_type(4))) float f32x4;
typedef __attribute__((ext_vector_type(8))) _Float16 f16x8;
typedef __attribute__((ext_vector_type(4))) _Float16 f16x4;
typedef __attribute__((ext_vector_type(8))) unsigned short u16x8;

__device__ inline unsigned short f2bf(float x) {
    unsigned u = __float_as_uint(x);
    unsigned r = (u + 0x7FFFu + ((u >> 16) & 1u)) >> 16;  // RNE
    return (unsigned short)r;
}

__device__ inline float h2f(unsigned hb) {
    return (float)__builtin_bit_cast(_Float16, (unsigned short)hb);
}

// Kernel 0: fp32 -> bf16 copy + per-row sum of squares.
__global__ __launch_bounds__(256) void prep_kernel(const float* __restrict__ E,
                                                   unsigned short* __restrict__ Ebf,
                                                   float* __restrict__ sq) {
    const int r = blockIdx.x;
    const int tid = threadIdx.x;
    const float4 v = ((const float4*)(E + (size_t)r * D))[tid];
    ushort4 o;
    o.x = f2bf(v.x); o.y = f2bf(v.y); o.z = f2bf(v.z); o.w = f2bf(v.w);
    ((ushort4*)(Ebf + (size_t)r * D))[tid] = o;
    float s = v.x * v.x + v.y * v.y + v.z * v.z + v.w * v.w;
    for (int off = 32; off > 0; off >>= 1) s += __shfl_down(s, off);
    __shared__ float red[4];
    const int lane = tid & 63, wave = tid >> 6;
    if (lane == 0) red[wave] = s;
    __syncthreads();
    if (tid == 0) sq[r] = red[0] + red[1] + red[2] + red[3];
}

// Kernel 0b: target int32 -> uchar class ids (N_CLASSES=128 fits).
__global__ __launch_bounds__(256) void cls_kernel(const int* __restrict__ target,
                                                  unsigned char* __restrict__ cls) {
    const int t = blockIdx.x * 256 + threadIdx.x;
    cls[t] = (unsigned char)target[t];
}

// Kernel 1 (round-5 version, reverted): symmetric D2, lower-tri 128x128 blocks,
// mirror tile via LDS transpose.
__global__ __launch_bounds__(256) void gemm_kernel(const unsigned short* __restrict__ E,
                                                   const float* __restrict__ sq,
                                                   _Float16* __restrict__ D2h) {
    __shared__ char smem[128 * 136 * 2];                  // 34816 B
    unsigned short* As = (unsigned short*)smem;           // 8 KB (K-loop)
    unsigned short* Bs = (unsigned short*)(smem + 8192);  // 8 KB (K-loop)
    _Float16* Ts = (_Float16*)smem;                       // 128 x (stride 136) fp16 (epilogue)

    const int tid = threadIdx.x;
    const int lane = tid & 63;
    const int wave = tid >> 6;
    const int wm = wave & 1, wn = wave >> 1;

    // decode linear block id -> (bx, by) with by >= bx
    const int l = blockIdx.x;
    int by = (int)((sqrtf(8.0f * (float)l + 1.0f) - 1.0f) * 0.5f);
    while ((by + 1) * (by + 2) / 2 <= l) ++by;
    while (by * (by + 1) / 2 > l) --by;
    const int bx = l - by * (by + 1) / 2;
    const int rm = by * 128;
    const int cn = bx * 128;

    const int srow = tid >> 2;
    const int scol = (tid & 3) * 8;

    const unsigned short* gA = E + (size_t)(rm + srow) * D + scol;
    const unsigned short* gB = E + (size_t)(cn + srow) * D + scol;

    f32x4 acc[4][4] = {};

    const int kq = (lane >> 4) * 8;
    const int mr = lane & 15;

    for (int k0 = 0; k0 < D; k0 += 32) {
        __builtin_amdgcn_global_load_lds(
            (const __attribute__((address_space(1))) unsigned int*)(gA + k0),
            (__attribute__((address_space(3))) unsigned int*)((char*)As + wave * 1024), 16, 0, 0);
        __builtin_amdgcn_global_load_lds(
            (const __attribute__((address_space(1))) unsigned int*)(gA + (size_t)64 * D + k0),
            (__attribute__((address_space(3))) unsigned int*)((char*)As + 4096 + wave * 1024), 16, 0, 0);
        __builtin_amdgcn_global_load_lds(
            (const __attribute__((address_space(1))) unsigned int*)(gB + k0),
            (__attribute__((address_space(3))) unsigned int*)((char*)Bs + wave * 1024), 16, 0, 0);
        __builtin_amdgcn_global_load_lds(
            (const __attribute__((address_space(1))) unsigned int*)(gB + (size_t)64 * D + k0),
            (__attribute__((address_space(3))) unsigned int*)((char*)Bs + 4096 + wave * 1024), 16, 0, 0);
        __syncthreads();

        bf16x8 af[4], bfr[4];
#pragma unroll
        for (int mi = 0; mi < 4; ++mi)
            af[mi] = *(const bf16x8*)(As + (wm * 64 + mi * 16 + mr) * 32 + kq);
#pragma unroll
        for (int ni = 0; ni < 4; ++ni)
            bfr[ni] = *(const bf16x8*)(Bs + (wn * 64 + ni * 16 + mr) * 32 + kq);
#pragma unroll
        for (int mi = 0; mi < 4; ++mi)
#pragma unroll
            for (int ni = 0; ni < 4; ++ni)
                acc[mi][ni] = __builtin_amdgcn_mfma_f32_16x16x32_bf16(af[mi], bfr[ni], acc[mi][ni], 0, 0, 0);
        __syncthreads();
    }

    const int crow = (lane >> 4) * 4;
    const int ccol = lane & 15;
    const bool offdiag = (bx != by);
    float sqj[4];
#pragma unroll
    for (int ni = 0; ni < 4; ++ni)
        sqj[ni] = sq[cn + wn * 64 + ni * 16 + ccol];
#pragma unroll
    for (int mi = 0; mi < 4; ++mi) {
        const int lrow = wm * 64 + mi * 16 + crow;
        const int i0 = rm + lrow;
        float sqi[4];
#pragma unroll
        for (int r = 0; r < 4; ++r) sqi[r] = sq[i0 + r];
#pragma unroll
        for (int ni = 0; ni < 4; ++ni) {
            const int lcol = wn * 64 + ni * 16 + ccol;
            const int j = cn + lcol;
            f16x4 tv;
#pragma unroll
            for (int r = 0; r < 4; ++r) {
                float d2 = fmaxf(sqi[r] + sqj[ni] - 2.0f * acc[mi][ni][r], 0.0f);
                _Float16 h = (_Float16)d2;
                D2h[(size_t)(i0 + r) * N + j] = h;
                tv[r] = h;
            }
            if (offdiag)
                *(f16x4*)(Ts + (size_t)lcol * 136 + lrow) = tv;
        }
    }
    if (offdiag) {
        __syncthreads();
#pragma unroll
        for (int it = 0; it < 8; ++it) {
            const int rt = it * 16 + (tid >> 4);
            const int seg = tid & 15;
            f16x8 v = *(const f16x8*)(Ts + (size_t)rt * 136 + seg * 8);
            *(f16x8*)(D2h + (size_t)(cn + rt) * N + rm + seg * 8) = v;
        }
    }
}

// Kernel 2: one BLOCK per anchor row, single global pass, value-only mining.
// Non-negative fp16 orders as u16 bits, so all reductions are u32 max/min on
// raw half-bits. Pass 2 runs from a 16-VGPR register stash (32 elems/thread).
// Loss from fp16 d2 values directly (index-free; EPS effect ~1e-6, negligible).
__global__ __launch_bounds__(256) void mine_kernel(const _Float16* __restrict__ D2h,
                                                   const unsigned char* __restrict__ cls,
                                                   float* __restrict__ loss_arr) {
    const int i = blockIdx.x;
    const int tid = threadIdx.x;
    const int lane = tid & 63, wave = tid >> 6;
    const unsigned tcb = cls[i];
    const unsigned short* row = (const unsigned short*)(D2h + (size_t)i * N);

    u16x8 v[4];
    unsigned long long c8[4];
#pragma unroll
    for (int it = 0; it < 4; ++it) {
        v[it] = *(const u16x8*)(row + it * 2048 + tid * 8);
        c8[it] = *(const unsigned long long*)(cls + it * 2048 + tid * 8);
    }

    // Pass 1: pm = max same-class bits (self ~0, never max); nm = min diff-class bits.
    unsigned pm = 0u, nm = 0xFFFFu;
#pragma unroll
    for (int it = 0; it < 4; ++it) {
#pragma unroll
        for (int e = 0; e < 8; ++e) {
            const unsigned hb = v[it][e];
            const bool s = ((unsigned)(c8[it] >> (8 * e)) & 0xFFu) == tcb;
            pm = max(pm, s ? hb : 0u);
            nm = min(nm, s ? 0xFFFFu : hb);
        }
    }
    for (int off = 1; off < 64; off <<= 1) {
        pm = max(pm, (unsigned)__shfl_xor((int)pm, off));
        nm = min(nm, (unsigned)__shfl_xor((int)nm, off));
    }
    __shared__ unsigned redp[4], redn[4], reds[4];
    if (lane == 0) { redp[wave] = pm; redn[wave] = nm; }
    __syncthreads();
    pm = max(max(redp[0], redp[1]), max(redp[2], redp[3]));
    nm = min(min(redn[0], redn[1]), min(redn[2], redn[3]));
    const unsigned lob = pm;

    // Pass 2 (register stash): sm = min bits strictly above lob.
    // Strict > excludes all positives (<= lob) and self. No class test needed.
    unsigned sm = 0xFFFFu;
#pragma unroll
    for (int it = 0; it < 4; ++it) {
#pragma unroll
        for (int e = 0; e < 8; ++e) {
            const unsigned hb = v[it][e];
            sm = min(sm, hb > lob ? hb : 0xFFFFu);
        }
    }
    for (int off = 1; off < 64; off <<= 1)
        sm = min(sm, (unsigned)__shfl_xor((int)sm, off));
    if (lane == 0) reds[wave] = sm;
    __syncthreads();
    if (tid == 0) {
        sm = min(min(reds[0], reds[1]), min(reds[2], reds[3]));
        const float lo = h2f(lob);
        const float dp = sqrtf(lo);
        const float hw = dp + MARGIN;
        const float hi = hw * hw;
        const float smv = h2f(sm);                   // 0xFFFF -> NaN -> fallback
        const float dn2 = (smv < hi) ? smv : h2f(nm);
        loss_arr[i] = fmaxf(dp - sqrtf(dn2) + MARGIN, 0.0f);
    }
}

// Kernel 3: mean over 8192 per-anchor losses.
__global__ __launch_bounds__(256) void reduce_kernel(const float* __restrict__ loss_arr,
                                                     float* __restrict__ out) {
    const int tid = threadIdx.x;
    float s = 0.0f;
    for (int k = tid; k < N; k += 256) s += loss_arr[k];
    for (int off = 32; off > 0; off >>= 1) s += __shfl_down(s, off);
    __shared__ float red[4];
    const int lane = tid & 63, wave = tid >> 6;
    if (lane == 0) red[wave] = s;
    __syncthreads();
    if (tid == 0) out[0] = (red[0] + red[1] + red[2] + red[3]) * (1.0f / N);
}

extern "C" void kernel_launch(void* const* d_in, const int* in_sizes, int n_in,
                              void* d_out, int out_size, void* d_ws, size_t ws_size,
                              hipStream_t stream) {
    const float* E = (const float*)d_in[0];
    const int* target = (const int*)d_in[1];
    float* out = (float*)d_out;
    char* ws = (char*)d_ws;

    // Workspace layout (~144.1 MB):
    unsigned short* Ebf = (unsigned short*)ws;                            // 16 MB
    float* sq        = (float*)(ws + (size_t)16777216);                   // 32 KB
    float* loss_arr  = (float*)(ws + (size_t)16809984);                   // 32 KB
    unsigned char* cls = (unsigned char*)(ws + (size_t)16842752);         // 8 KB (padded 32 KB)
    _Float16* D2h    = (_Float16*)(ws + (size_t)16875520);                // 128 MB

    prep_kernel<<<N, 256, 0, stream>>>(E, Ebf, sq);
    cls_kernel<<<N / 256, 256, 0, stream>>>(target, cls);
    gemm_kernel<<<2080, 256, 0, stream>>>(Ebf, sq, D2h);  // 64*65/2 lower-tri blocks
    mine_kernel<<<N, 256, 0, stream>>>(D2h, cls, loss_arr);
    reduce_kernel<<<1, 256, 0, stream>>>(loss_arr, out);
}